// Round 1
// baseline (262.451 us; speedup 1.0000x reference)
//
#include <hip/hip_runtime.h>

typedef unsigned short u16;
typedef __attribute__((ext_vector_type(8))) short bf16x8;
typedef __attribute__((ext_vector_type(4))) float f32x4;

#define MFMA16x16x32(a, b, c) __builtin_amdgcn_mfma_f32_16x16x32_bf16((a), (b), (c), 0, 0, 0)
#define F4C(v, u) (((const float*)&(v))[u])

// round-to-nearest-even f32 -> bf16
static __device__ __forceinline__ u16 f2bf(float x) {
  unsigned int u = __float_as_uint(x);
  u += 0x7FFFu + ((u >> 16) & 1u);
  return (u16)(u >> 16);
}

// ---------------------------------------------------------------------------
// Kernel 1: five 1x1-conv projections (fp32 compute, bf16 outputs)
// Q,Kh,Km stored (B,N,64) [key/pixel rows, d contiguous]  -> MFMA frag = 16B load
// Vh,Vm stored (B,C,N) [c rows, pixel contiguous]         -> MFMA B-frag = 16B load
// grid (16 ntiles, 16 batches), block 256
// ---------------------------------------------------------------------------
__global__ __launch_bounds__(256) void proj_kernel(
    const float* __restrict__ h, const float* __restrict__ m_,
    const float* __restrict__ Wq, const float* __restrict__ bq,
    const float* __restrict__ Wk, const float* __restrict__ bk,
    const float* __restrict__ Wk2, const float* __restrict__ bk2,
    const float* __restrict__ Wv, const float* __restrict__ bv,
    const float* __restrict__ Wv2, const float* __restrict__ bv2,
    u16* __restrict__ Qb, u16* __restrict__ Khb, u16* __restrict__ Kmb,
    u16* __restrict__ Vhb, u16* __restrict__ Vmb)
{
  const int b = blockIdx.y;
  const int n0 = blockIdx.x * 64;
  __shared__ float ht[64][64];
  __shared__ float mt[64][64];
  __shared__ float st[64][65];
  const int tid = threadIdx.x;

  for (int idx = tid; idx < 4096; idx += 256) {
    const int c = idx >> 6, px = idx & 63;
    ht[c][px] = h [(b * 64 + c) * 1024 + n0 + px];
    mt[c][px] = m_[(b * 64 + c) * 1024 + n0 + px];
  }
  __syncthreads();

  const int o = tid & 63;
  const int pg = tid >> 6;
  const int p0 = pg * 16;

  float acc[16];

  auto dot = [&](const float (*T)[64], const float* __restrict__ W,
                 const float* __restrict__ bias) {
    const float bz = bias[o];
#pragma unroll
    for (int i = 0; i < 16; ++i) acc[i] = bz;
    for (int c4 = 0; c4 < 16; ++c4) {
      const float4 wv = *(const float4*)(W + o * 64 + c4 * 4);
#pragma unroll
      for (int u = 0; u < 4; ++u) {
        const float wc = F4C(wv, u);
        const float* Tr = &T[c4 * 4 + u][p0];
#pragma unroll
        for (int g = 0; g < 4; ++g) {
          const float4 tv = *(const float4*)(Tr + g * 4);
          acc[g * 4 + 0] += wc * tv.x;
          acc[g * 4 + 1] += wc * tv.y;
          acc[g * 4 + 2] += wc * tv.z;
          acc[g * 4 + 3] += wc * tv.w;
        }
      }
    }
  };

  // Q (from h): direct (B,N,64) store, lanes over o -> coalesced
  dot(ht, Wq, bq);
#pragma unroll
  for (int i = 0; i < 16; ++i) Qb[(b * 1024 + n0 + p0 + i) * 64 + o] = f2bf(acc[i]);

  // Kh (from h), Km (from m): same layout
  dot(ht, Wk, bk);
#pragma unroll
  for (int i = 0; i < 16; ++i) Khb[(b * 1024 + n0 + p0 + i) * 64 + o] = f2bf(acc[i]);

  dot(mt, Wk2, bk2);
#pragma unroll
  for (int i = 0; i < 16; ++i) Kmb[(b * 1024 + n0 + p0 + i) * 64 + o] = f2bf(acc[i]);

  // Vh (from h): (B,C,N) -> transpose-stage through LDS for coalesced store
  dot(ht, Wv, bv);
#pragma unroll
  for (int i = 0; i < 16; ++i) st[o][p0 + i] = acc[i];
  __syncthreads();
  for (int idx = tid; idx < 4096; idx += 256) {
    const int c = idx >> 6, px = idx & 63;
    Vhb[(b * 64 + c) * 1024 + n0 + px] = f2bf(st[c][px]);
  }
  __syncthreads();

  // Vm (from m)
  dot(mt, Wv2, bv2);
#pragma unroll
  for (int i = 0; i < 16; ++i) st[o][p0 + i] = acc[i];
  __syncthreads();
  for (int idx = tid; idx < 4096; idx += 256) {
    const int c = idx >> 6, px = idx & 63;
    Vmb[(b * 64 + c) * 1024 + n0 + px] = f2bf(st[c][px]);
  }
}

// ---------------------------------------------------------------------------
// Kernel 2: fused attention (both branches), bf16 MFMA, 2-pass softmax.
// grid (16 rowblocks, 16 batches, 2 branches), block 256 (4 waves x 16 rows)
// Zt output: (B, N, 128) fp32, channel = br*64 + c
// ---------------------------------------------------------------------------
__global__ __launch_bounds__(256) void attn_kernel(
    const u16* __restrict__ Qb, const u16* __restrict__ Khb, const u16* __restrict__ Kmb,
    const u16* __restrict__ Vhb, const u16* __restrict__ Vmb, float* __restrict__ Zt)
{
  const int b = blockIdx.y;
  const int br = blockIdx.z;
  const u16* __restrict__ Kb = br ? Kmb : Khb;
  const u16* __restrict__ Vb = br ? Vmb : Vhb;

  const int tid = threadIdx.x;
  const int w = tid >> 6;
  const int lane = tid & 63;
  const int m = lane & 15;       // col index holder
  const int q = lane >> 4;       // quad
  const int row0 = blockIdx.x * 64 + w * 16;  // this wave's first Q row

  __shared__ __align__(16) u16 ps[4][16][40];  // per-wave P chunk [16 rows][32 j], pad 40

  // A-frags for this wave's 16 Q rows (row = lane&15), k = kc*32 + q*8 + j
  const u16* Qp = Qb + (b * 1024 + row0 + m) * 64;
  const bf16x8 aq0 = *(const bf16x8*)(Qp + q * 8);
  const bf16x8 aq1 = *(const bf16x8*)(Qp + 32 + q * 8);

  // ---- Pass 1: row sums of exp(S). No max-shift needed: |s| <~ 10 << 88.
  float rs0 = 0.f, rs1 = 0.f, rs2 = 0.f, rs3 = 0.f;
  for (int jt = 0; jt < 64; ++jt) {
    const u16* Kp = Kb + (b * 1024 + jt * 16 + m) * 64;
    const bf16x8 b0 = *(const bf16x8*)(Kp + q * 8);
    const bf16x8 b1 = *(const bf16x8*)(Kp + 32 + q * 8);
    f32x4 s = {0.f, 0.f, 0.f, 0.f};
    s = MFMA16x16x32(aq0, b0, s);
    s = MFMA16x16x32(aq1, b1, s);
    rs0 += __expf(s[0]);
    rs1 += __expf(s[1]);
    rs2 += __expf(s[2]);
    rs3 += __expf(s[3]);
  }
  float rs[4] = {rs0, rs1, rs2, rs3};
#pragma unroll
  for (int r = 0; r < 4; ++r) {
    float v = rs[r];
    v += __shfl_xor(v, 1);
    v += __shfl_xor(v, 2);
    v += __shfl_xor(v, 4);
    v += __shfl_xor(v, 8);
    rs[r] = 1.0f / v;   // reciprocal row sum for rows q*4+r
  }

  // ---- Pass 2: recompute S tile, P = exp(s)*rinv -> bf16 -> LDS (layout
  // transform C/D -> A-operand), then PV MFMA.
  f32x4 z0 = {0.f,0.f,0.f,0.f}, z1 = {0.f,0.f,0.f,0.f};
  f32x4 z2 = {0.f,0.f,0.f,0.f}, z3 = {0.f,0.f,0.f,0.f};

  for (int jc = 0; jc < 32; ++jc) {
    __syncthreads();  // WAR: prior iter's reads done before overwriting ps
#pragma unroll
    for (int t = 0; t < 2; ++t) {
      const u16* Kp = Kb + (b * 1024 + jc * 32 + t * 16 + m) * 64;
      const bf16x8 b0 = *(const bf16x8*)(Kp + q * 8);
      const bf16x8 b1 = *(const bf16x8*)(Kp + 32 + q * 8);
      f32x4 s = {0.f, 0.f, 0.f, 0.f};
      s = MFMA16x16x32(aq0, b0, s);
      s = MFMA16x16x32(aq1, b1, s);
#pragma unroll
      for (int r = 0; r < 4; ++r)
        ps[w][q * 4 + r][t * 16 + m] = f2bf(__expf(s[r]) * rs[r]);
    }
    __syncthreads();  // writes visible before A-frag reads

    const bf16x8 ap = *(const bf16x8*)&ps[w][m][q * 8];  // A[m][k=q*8+j]

#pragma unroll
    for (int ct = 0; ct < 4; ++ct) {
      const u16* Vp = Vb + (b * 64 + ct * 16 + m) * 1024 + jc * 32 + q * 8;
      const bf16x8 bv = *(const bf16x8*)Vp;  // B[k=j][n=c], j contiguous
      if (ct == 0) z0 = MFMA16x16x32(ap, bv, z0);
      else if (ct == 1) z1 = MFMA16x16x32(ap, bv, z1);
      else if (ct == 2) z2 = MFMA16x16x32(ap, bv, z2);
      else z3 = MFMA16x16x32(ap, bv, z3);
    }
  }

  // Store Z^T tile: rows q*4+r, channel ct*16+m -> (B,N,128)
  const int chb = br * 64 + m;
#pragma unroll
  for (int r = 0; r < 4; ++r) {
    const int n = row0 + q * 4 + r;
    float* Zr = Zt + (b * 1024 + n) * 128 + chb;
    Zr[0]  = z0[r];
    Zr[16] = z1[r];
    Zr[32] = z2[r];
    Zr[48] = z3[r];
  }
}

// ---------------------------------------------------------------------------
// Kernel 3: Z projection, 128->128 fp32 GEMM per pixel.
// Zt (B,N,128) -> Zp (B,N,128). grid (16,16), block 256.
// ---------------------------------------------------------------------------
__global__ __launch_bounds__(256) void zproj_kernel(
    const float* __restrict__ Zt, const float* __restrict__ Wz,
    const float* __restrict__ bz, float* __restrict__ Zp)
{
  const int b = blockIdx.y, n0 = blockIdx.x * 64;
  __shared__ float zt[128][64];  // XOR-swizzled pixel groups
  const int tid = threadIdx.x;

  for (int idx = tid; idx < 8192; idx += 256) {
    const int px = idx >> 7, c = idx & 127;
    zt[c][(px & 3) + 4 * ((px >> 2) ^ (c & 15))] = Zt[(b * 1024 + n0 + px) * 128 + c];
  }
  __syncthreads();

  const int o = tid & 127;
  const int pg = tid >> 7;  // 0..1, 32 px each
  float acc[32];
  const float bias = bz[o];
#pragma unroll
  for (int i = 0; i < 32; ++i) acc[i] = bias;

  for (int c4 = 0; c4 < 32; ++c4) {
    const float4 wv = *(const float4*)(Wz + o * 128 + c4 * 4);
#pragma unroll
    for (int u = 0; u < 4; ++u) {
      const int c = c4 * 4 + u;
      const float wc = F4C(wv, u);
      const float* zr = zt[c];
      const int sw = c & 15;
#pragma unroll
      for (int g = 0; g < 8; ++g) {
        const int gl = pg * 8 + g;
        const float4 v = *(const float4*)(zr + 4 * (gl ^ sw));
        acc[g * 4 + 0] += wc * v.x;
        acc[g * 4 + 1] += wc * v.y;
        acc[g * 4 + 2] += wc * v.z;
        acc[g * 4 + 3] += wc * v.w;
      }
    }
  }

#pragma unroll
  for (int i = 0; i < 32; ++i) {
    const int px = pg * 32 + i;
    Zp[(b * 1024 + n0 + px) * 128 + o] = acc[i];
  }
}

// ---------------------------------------------------------------------------
// Kernel 4: combined = Wm @ [Zp; h] + bm; gates; outputs new_h, new_m.
// grid (16,16), block 256. LDS = exactly 64 KB.
// ---------------------------------------------------------------------------
__global__ __launch_bounds__(256) void final_kernel(
    const float* __restrict__ Zp, const float* __restrict__ h,
    const float* __restrict__ m_, const float* __restrict__ Wm,
    const float* __restrict__ bm, float* __restrict__ out)
{
  const int b = blockIdx.y, n0 = blockIdx.x * 64;
  __shared__ float it[192][64];   // concat input tile, XOR-swizzled
  __shared__ float mt4[64][64];   // m tile, rotation-swizzled
  const int tid = threadIdx.x;

  for (int idx = tid; idx < 8192; idx += 256) {
    const int px = idx >> 7, c = idx & 127;
    it[c][(px & 3) + 4 * ((px >> 2) ^ (c & 15))] = Zp[(b * 1024 + n0 + px) * 128 + c];
  }
  for (int idx = tid; idx < 4096; idx += 256) {
    const int c = idx >> 6, px = idx & 63;
    const int k = 128 + c;
    it[k][(px & 3) + 4 * ((px >> 2) ^ (k & 15))] = h[(b * 64 + c) * 1024 + n0 + px];
    mt4[c][(px + c) & 63] = m_[(b * 64 + c) * 1024 + n0 + px];
  }
  __syncthreads();

  const int c = tid & 63;
  const int pg = tid >> 6;  // 0..3, 16 px each
  float ao[16], ag[16], ai[16];
  const float bo = bm[c], bg = bm[64 + c], bi = bm[128 + c];
#pragma unroll
  for (int i = 0; i < 16; ++i) { ao[i] = bo; ag[i] = bg; ai[i] = bi; }

  for (int k4 = 0; k4 < 48; ++k4) {
    const float4 wo = *(const float4*)(Wm + c * 192 + k4 * 4);
    const float4 wg = *(const float4*)(Wm + (64 + c) * 192 + k4 * 4);
    const float4 wi = *(const float4*)(Wm + (128 + c) * 192 + k4 * 4);
#pragma unroll
    for (int u = 0; u < 4; ++u) {
      const int k = k4 * 4 + u;
      const float xo = F4C(wo, u), xg = F4C(wg, u), xi = F4C(wi, u);
      const float* ir = it[k];
      const int sw = k & 15;
#pragma unroll
      for (int g = 0; g < 4; ++g) {
        const int gl = pg * 4 + g;
        const float4 v = *(const float4*)(ir + 4 * (gl ^ sw));
        ao[g * 4 + 0] += xo * v.x; ao[g * 4 + 1] += xo * v.y;
        ao[g * 4 + 2] += xo * v.z; ao[g * 4 + 3] += xo * v.w;
        ag[g * 4 + 0] += xg * v.x; ag[g * 4 + 1] += xg * v.y;
        ag[g * 4 + 2] += xg * v.z; ag[g * 4 + 3] += xg * v.w;
        ai[g * 4 + 0] += xi * v.x; ai[g * 4 + 1] += xi * v.y;
        ai[g * 4 + 2] += xi * v.z; ai[g * 4 + 3] += xi * v.w;
      }
    }
  }

  __syncthreads();  // everyone done reading `it` -> reuse as staging
  float* nh = &it[0][0];
  float* nm = nh + 64 * 65;

#pragma unroll
  for (int i = 0; i < 16; ++i) {
    const int px = pg * 16 + i;
    const float mi = 1.0f / (1.0f + __expf(-ai[i]));
    float gx = fminf(fmaxf(ag[i], -30.f), 30.f);
    const float e2 = __expf(2.0f * gx);
    const float th = (e2 - 1.0f) / (e2 + 1.0f);
    const float mv = mt4[c][(px + c) & 63];
    const float nmv = (1.0f - mi) * mv + mi * th;
    const float nhv = nmv / (1.0f + __expf(-ao[i]));
    nh[c * 65 + px] = nhv;
    nm[c * 65 + px] = nmv;
  }
  __syncthreads();

  for (int idx = tid; idx < 4096; idx += 256) {
    const int cc = idx >> 6, px = idx & 63;
    out[(b * 64 + cc) * 1024 + n0 + px]           = nh[cc * 65 + px];
    out[1048576 + (b * 64 + cc) * 1024 + n0 + px] = nm[cc * 65 + px];
  }
}

// ---------------------------------------------------------------------------
extern "C" void kernel_launch(void* const* d_in, const int* in_sizes, int n_in,
                              void* d_out, int out_size, void* d_ws, size_t ws_size,
                              hipStream_t stream) {
  const float* h   = (const float*)d_in[0];
  const float* m   = (const float*)d_in[1];
  const float* Wq  = (const float*)d_in[2];
  const float* bq  = (const float*)d_in[3];
  const float* Wk  = (const float*)d_in[4];
  const float* bk  = (const float*)d_in[5];
  const float* Wk2 = (const float*)d_in[6];
  const float* bk2 = (const float*)d_in[7];
  const float* Wv  = (const float*)d_in[8];
  const float* bv  = (const float*)d_in[9];
  const float* Wv2 = (const float*)d_in[10];
  const float* bv2 = (const float*)d_in[11];
  const float* Wz  = (const float*)d_in[12];
  const float* bz  = (const float*)d_in[13];
  const float* Wm  = (const float*)d_in[14];
  const float* bm  = (const float*)d_in[15];
  float* out = (float*)d_out;

  // workspace layout (26 MB total)
  u16* Qb  = (u16*)d_ws;            // 1M bf16
  u16* Khb = Qb  + (1u << 20);
  u16* Kmb = Khb + (1u << 20);
  u16* Vhb = Kmb + (1u << 20);
  u16* Vmb = Vhb + (1u << 20);
  float* Zt = (float*)(Vmb + (1u << 20));  // 2M fp32 (B,N,128)
  float* Zp = Zt + (1u << 21);             // 2M fp32 (B,N,128)

  proj_kernel<<<dim3(16, 16), 256, 0, stream>>>(h, m, Wq, bq, Wk, bk, Wk2, bk2,
                                                Wv, bv, Wv2, bv2,
                                                Qb, Khb, Kmb, Vhb, Vmb);
  attn_kernel<<<dim3(16, 16, 2), 256, 0, stream>>>(Qb, Khb, Kmb, Vhb, Vmb, Zt);
  zproj_kernel<<<dim3(16, 16), 256, 0, stream>>>(Zt, Wz, bz, Zp);
  final_kernel<<<dim3(16, 16), 256, 0, stream>>>(Zp, h, m, Wm, bm, out);
}

// Round 2
// 140.798 us; speedup vs baseline: 1.8640x; 1.8640x over previous
//
#include <hip/hip_runtime.h>

typedef unsigned short u16;
typedef unsigned int u32;
typedef __attribute__((ext_vector_type(8))) short bf16x8;
typedef __attribute__((ext_vector_type(4))) float f32x4;

#define MFMA(a, b, c) __builtin_amdgcn_mfma_f32_16x16x32_bf16((a), (b), (c), 0, 0, 0)

// round-to-nearest-even f32 -> bf16
static __device__ __forceinline__ u16 f2bf(float x) {
  u32 u = __float_as_uint(x);
  u += 0x7FFFu + ((u >> 16) & 1u);
  return (u16)(u >> 16);
}
// truncating f32 -> bf16 (cheap; used on hot paths, ~0.4% rel err)
static __device__ __forceinline__ u16 f2bf_t(float x) {
  return (u16)(__float_as_uint(x) >> 16);
}

// ---------------------------------------------------------------------------
// Kernel 0: weight prep. bf16-convert all GEMM weights; permute Wm rows
// gate-major so the tail kernel's per-wave D-tiles contain complete
// (mo,mg,mi) triples. Runs every launch (ws is re-poisoned).
// ---------------------------------------------------------------------------
__global__ void prep_kernel(const float* __restrict__ Wq, const float* __restrict__ Wk,
                            const float* __restrict__ Wk2, const float* __restrict__ Wv,
                            const float* __restrict__ Wv2, const float* __restrict__ Wz,
                            const float* __restrict__ Wm, const float* __restrict__ bm,
                            u16* __restrict__ W5, u16* __restrict__ Wzb,
                            u16* __restrict__ Wmb, float* __restrict__ bmp) {
  const int id = blockIdx.x * 256 + threadIdx.x;
  if (id < 20480) {
    const int wi = id >> 12, e = id & 4095;
    const float* src = wi == 0 ? Wq : wi == 1 ? Wk : wi == 2 ? Wk2 : wi == 3 ? Wv : Wv2;
    W5[id] = f2bf(src[e]);
  } else if (id < 36864) {
    const int e = id - 20480;
    Wzb[e] = f2bf(Wz[e]);
  } else if (id < 73728) {
    const int e = id - 36864;
    const int p = e / 192, k = e % 192;
    const int hb2 = p / 96, r1 = p % 96, ctl = r1 / 48, r2 = r1 % 48;
    const int g = r2 >> 4, mm = r2 & 15;
    const int o = g * 64 + (hb2 * 2 + ctl) * 16 + mm;
    Wmb[p * 192 + k] = f2bf(Wm[o * 192 + k]);
  } else if (id < 73920) {
    const int p = id - 73728;
    const int hb2 = p / 96, r1 = p % 96, ctl = r1 / 48, r2 = r1 % 48;
    const int g = r2 >> 4, mm = r2 & 15;
    const int o = g * 64 + (hb2 * 2 + ctl) * 16 + mm;
    bmp[p] = bm[o];
  }
}

// ---------------------------------------------------------------------------
// Kernel 1: 1x1-conv projections via bf16 MFMA.
// grid (16 ntiles, 16 batches, 2): z=0 -> Q,Kh,Vh from h (+ hb store);
//                                  z=1 -> Km,Vm from m.
// Q,K stored (B,N,64); V stored (B,C,N); hb (B,N,64).
// ---------------------------------------------------------------------------
__global__ __launch_bounds__(256) void proj_kernel(
    const float* __restrict__ h, const float* __restrict__ m_,
    const float* __restrict__ bq, const float* __restrict__ bk,
    const float* __restrict__ bk2, const float* __restrict__ bv,
    const float* __restrict__ bv2, const u16* __restrict__ W5,
    u16* __restrict__ Qb, u16* __restrict__ Khb, u16* __restrict__ Kmb,
    u16* __restrict__ Vhb, u16* __restrict__ Vmb, u16* __restrict__ hbuf)
{
  const int b = blockIdx.y, n0 = blockIdx.x * 64, z = blockIdx.z;
  __shared__ __align__(16) u16 xt[64][72];  // transposed bf16 input [px][c]
  __shared__ __align__(16) u16 st[64][72];  // V bounce [c][px]
  const int tid = threadIdx.x;
  const float* __restrict__ X = z ? m_ : h;

  {
    const int px = tid & 63, c0 = tid >> 6;
#pragma unroll
    for (int i = 0; i < 16; ++i) {
      const int c = c0 * 16 + i;
      xt[px][c] = f2bf(X[(b * 64 + c) * 1024 + n0 + px]);
    }
  }
  __syncthreads();

  const int lane = tid & 63, w = tid >> 6;  // w = px-tile
  const int mm = lane & 15, q = lane >> 4;

  const bf16x8 xa0 = *(const bf16x8*)&xt[w * 16 + mm][q * 8];
  const bf16x8 xa1 = *(const bf16x8*)&xt[w * 16 + mm][32 + q * 8];

  auto gemm_tile = [&](const u16* Wb, const float* bias, int ot) -> f32x4 {
    const bf16x8 b0 = *(const bf16x8*)(Wb + (ot * 16 + mm) * 64 + q * 8);
    const bf16x8 b1 = *(const bf16x8*)(Wb + (ot * 16 + mm) * 64 + 32 + q * 8);
    const float bb = bias[ot * 16 + mm];
    f32x4 d = {bb, bb, bb, bb};
    d = MFMA(xa0, b0, d);
    d = MFMA(xa1, b1, d);
    return d;
  };

  auto store_nk = [&](u16* dst, const u16* Wb, const float* bias) {
#pragma unroll
    for (int ot = 0; ot < 4; ++ot) {
      const f32x4 d = gemm_tile(Wb, bias, ot);
#pragma unroll
      for (int r = 0; r < 4; ++r)
        dst[(b * 1024 + n0 + w * 16 + q * 4 + r) * 64 + ot * 16 + mm] = f2bf(d[r]);
    }
  };
  auto store_v = [&](const u16* Wb, const float* bias) {
#pragma unroll
    for (int ot = 0; ot < 4; ++ot) {
      const f32x4 d = gemm_tile(Wb, bias, ot);
#pragma unroll
      for (int r = 0; r < 4; ++r)
        st[ot * 16 + mm][w * 16 + q * 4 + r] = f2bf(d[r]);
    }
  };

  if (z == 0) {
    store_nk(Qb, W5, bq);
    store_nk(Khb, W5 + 4096, bk);
    store_v(W5 + 3 * 4096, bv);
    // hb: coalesced bf16 copy of transposed h tile
    const int px = tid >> 2, sg = tid & 3;
    u32* dst = (u32*)(hbuf + (b * 1024 + n0 + px) * 64 + sg * 16);
    const u16* srcr = &xt[px][sg * 16];
#pragma unroll
    for (int j = 0; j < 8; ++j) dst[j] = *(const u32*)(srcr + 2 * j);
  } else {
    store_nk(Kmb, W5 + 2 * 4096, bk2);
    store_v(W5 + 4 * 4096, bv2);
  }
  __syncthreads();
  {
    u16* Vdst = z ? Vmb : Vhb;
    const int c = tid >> 2, sg = tid & 3;
    u32* dst = (u32*)(Vdst + (b * 64 + c) * 1024 + n0 + sg * 16);
    const u16* srcr = &st[c][sg * 16];
#pragma unroll
    for (int j = 0; j < 8; ++j) dst[j] = *(const u32*)(srcr + 2 * j);
  }
}

// ---------------------------------------------------------------------------
// Kernel 2: fused attention, single-pass unnormalized softmax, barrier-free
// K-loop. Block = 4 waves x same 64 queries; keys split 4-way across waves;
// bf16 LDS combine at the end. grid: 1D 512, XCD-affine (b = id & 15).
// Output Ztb: (B,N,128) bf16, channel = br*64 + c.
// ---------------------------------------------------------------------------
__global__ __launch_bounds__(256) void attn_kernel(
    const u16* __restrict__ Qb, const u16* __restrict__ Khb,
    const u16* __restrict__ Kmb, const u16* __restrict__ Vhb,
    const u16* __restrict__ Vmb, u16* __restrict__ Ztb)
{
  const int id = blockIdx.x;
  const int b = id & 15, rest = id >> 4;
  const int br = rest & 1, qb0 = (rest >> 1) * 64;
  const u16* __restrict__ K = br ? Kmb : Khb;
  const u16* __restrict__ V = br ? Vmb : Vhb;

  __shared__ __align__(16) u16 ps[4][16][40];    // per-wave P chunk [q][key]
  __shared__ __align__(16) u16 zcb[4][64][66];   // bf16 partial Z [w][query][c]
  __shared__ __align__(16) float rsw[4][64];     // partial row sums

  const int tid = threadIdx.x, w = tid >> 6, lane = tid & 63;
  const int mm = lane & 15, q = lane >> 4;

  // Q A-frags for 4 query tiles (resident across the whole K range)
  bf16x8 qa0[4], qa1[4];
#pragma unroll
  for (int qt = 0; qt < 4; ++qt) {
    const u16* Qp = Qb + (b * 1024 + qb0 + qt * 16 + mm) * 64;
    qa0[qt] = *(const bf16x8*)(Qp + q * 8);
    qa1[qt] = *(const bf16x8*)(Qp + 32 + q * 8);
  }

  f32x4 z[4][4];  // [qt][ct] accumulator (unnormalized)
#pragma unroll
  for (int qt = 0; qt < 4; ++qt)
#pragma unroll
    for (int ct = 0; ct < 4; ++ct) z[qt][ct] = (f32x4){0.f, 0.f, 0.f, 0.f};
  float rp[4][4];  // [qt][r] partial exp row sums
#pragma unroll
  for (int qt = 0; qt < 4; ++qt)
#pragma unroll
    for (int r = 0; r < 4; ++r) rp[qt][r] = 0.f;

  const int kb0 = w * 256;  // this wave's key range
  for (int ch = 0; ch < 8; ++ch) {
    const int kb = kb0 + ch * 32;
    bf16x8 kf0[2], kf1[2];
#pragma unroll
    for (int t = 0; t < 2; ++t) {
      const u16* Kp = K + (b * 1024 + kb + t * 16 + mm) * 64;
      kf0[t] = *(const bf16x8*)(Kp + q * 8);
      kf1[t] = *(const bf16x8*)(Kp + 32 + q * 8);
    }
    bf16x8 vf[4];
#pragma unroll
    for (int ct = 0; ct < 4; ++ct)
      vf[ct] = *(const bf16x8*)(V + (b * 64 + ct * 16 + mm) * 1024 + kb + q * 8);

#pragma unroll
    for (int qt = 0; qt < 4; ++qt) {
#pragma unroll
      for (int t = 0; t < 2; ++t) {
        f32x4 s = {0.f, 0.f, 0.f, 0.f};
        s = MFMA(qa0[qt], kf0[t], s);
        s = MFMA(qa1[qt], kf1[t], s);
#pragma unroll
        for (int r = 0; r < 4; ++r) {
          const float e = __expf(s[r]);  // |s| <~ 10: no max-shift needed
          rp[qt][r] += e;
          ps[w][q * 4 + r][t * 16 + mm] = f2bf_t(e);
        }
      }
      // per-wave LDS round-trip: C-layout -> A-operand layout (same-wave
      // DS ordering; no barrier needed)
      const bf16x8 pa = *(const bf16x8*)&ps[w][mm][q * 8];
#pragma unroll
      for (int ct = 0; ct < 4; ++ct) z[qt][ct] = MFMA(pa, vf[ct], z[qt][ct]);
    }
  }

  // reduce row sums across the 16 key-col lanes
#pragma unroll
  for (int qt = 0; qt < 4; ++qt)
#pragma unroll
    for (int r = 0; r < 4; ++r) {
      float v = rp[qt][r];
      v += __shfl_xor(v, 1);
      v += __shfl_xor(v, 2);
      v += __shfl_xor(v, 4);
      v += __shfl_xor(v, 8);
      rp[qt][r] = v;
    }

  // publish partials
#pragma unroll
  for (int qt = 0; qt < 4; ++qt) {
#pragma unroll
    for (int ct = 0; ct < 4; ++ct)
#pragma unroll
      for (int r = 0; r < 4; ++r)
        zcb[w][qt * 16 + q * 4 + r][ct * 16 + mm] = f2bf_t(z[qt][ct][r]);
    if (mm == 0) {
#pragma unroll
      for (int r = 0; r < 4; ++r) rsw[w][qt * 16 + q * 4 + r] = rp[qt][r];
    }
  }
  __syncthreads();

  // combine 4 key-splits, normalize, store bf16 (B,N,128)
  const int c2 = tid & 31, q0 = tid >> 5;
#pragma unroll
  for (int i = 0; i < 8; ++i) {
    const int query = q0 + i * 8;
    const float rt = rsw[0][query] + rsw[1][query] + rsw[2][query] + rsw[3][query];
    const float rinv = __builtin_amdgcn_rcpf(rt);
    float vlo = 0.f, vhi = 0.f;
#pragma unroll
    for (int ww = 0; ww < 4; ++ww) {
      const u32 u = *(const u32*)&zcb[ww][query][c2 * 2];
      vlo += __uint_as_float(u << 16);
      vhi += __uint_as_float(u & 0xffff0000u);
    }
    vlo *= rinv;
    vhi *= rinv;
    const u32 o = __builtin_amdgcn_perm(__float_as_uint(vhi), __float_as_uint(vlo),
                                        0x07060302u);
    *(u32*)(Ztb + (b * 1024 + qb0 + query) * 128 + br * 64 + c2 * 2) = o;
  }
}

// ---------------------------------------------------------------------------
// Kernel 3: fused zproj (128->128) + final (192->192) + gates, all MFMA.
// grid (32 px-tiles, 16 b), block 256 (4 waves). Phase A waves: (pxt, o-half).
// Phase B waves: (pxt, gate-half) with gate-major-permuted Wmb.
// ---------------------------------------------------------------------------
__global__ __launch_bounds__(256) void tail_kernel(
    const u16* __restrict__ Ztb, const u16* __restrict__ hbuf,
    const float* __restrict__ m_, const u16* __restrict__ Wzb,
    const float* __restrict__ bz, const u16* __restrict__ Wmb,
    const float* __restrict__ bmp, float* __restrict__ out)
{
  const int b = blockIdx.y, n0 = blockIdx.x * 32;
  __shared__ __align__(16) u16 zp[32][136];  // bf16 Zp tile [px][c]
  const int tid = threadIdx.x, lane = tid & 63, wv = tid >> 6;
  const int mm = lane & 15, q = lane >> 4;
  const int pxt = wv & 1, oh = wv >> 1;

  // ---- Phase A: Zp = Wz @ [Zh;Zm] + bz
  {
    bf16x8 za[4];
#pragma unroll
    for (int ks = 0; ks < 4; ++ks)
      za[ks] = *(const bf16x8*)(Ztb + (b * 1024 + n0 + pxt * 16 + mm) * 128 +
                                ks * 32 + q * 8);
#pragma unroll
    for (int ot = 0; ot < 4; ++ot) {
      const int o = oh * 64 + ot * 16 + mm;
      const float bb = bz[o];
      f32x4 d = {bb, bb, bb, bb};
#pragma unroll
      for (int ks = 0; ks < 4; ++ks) {
        const bf16x8 wb = *(const bf16x8*)(Wzb + o * 128 + ks * 32 + q * 8);
        d = MFMA(za[ks], wb, d);
      }
#pragma unroll
      for (int r = 0; r < 4; ++r) zp[pxt * 16 + q * 4 + r][o] = f2bf(d[r]);
    }
  }
  __syncthreads();

  // ---- Phase B: combined = Wm @ [Zp; h] + bm (rows permuted gate-major)
  {
    const int hb2 = oh;
    bf16x8 fa[6];
#pragma unroll
    for (int ks = 0; ks < 4; ++ks)
      fa[ks] = *(const bf16x8*)&zp[pxt * 16 + mm][ks * 32 + q * 8];
    {
      const u16* hp = hbuf + (b * 1024 + n0 + pxt * 16 + mm) * 64;
      fa[4] = *(const bf16x8*)(hp + q * 8);
      fa[5] = *(const bf16x8*)(hp + 32 + q * 8);
    }
    f32x4 dd[6];
#pragma unroll
    for (int j = 0; j < 6; ++j) {
      const int p = hb2 * 96 + j * 16 + mm;
      const float bb = bmp[p];
      f32x4 d = {bb, bb, bb, bb};
#pragma unroll
      for (int ks = 0; ks < 6; ++ks) {
        const bf16x8 wb = *(const bf16x8*)(Wmb + p * 192 + ks * 32 + q * 8);
        d = MFMA(fa[ks], wb, d);
      }
      dd[j] = d;
    }
    // gates: j = ctl*3 + {o,g,i}
#pragma unroll
    for (int ctl = 0; ctl < 2; ++ctl) {
      const int c = (hb2 * 2 + ctl) * 16 + mm;
      const int px = n0 + pxt * 16 + q * 4;
      const float4 mold = *(const float4*)(m_ + (b * 64 + c) * 1024 + px);
      float4 nh, nm;
#pragma unroll
      for (int r = 0; r < 4; ++r) {
        const float xo = dd[ctl * 3 + 0][r];
        const float xg = dd[ctl * 3 + 1][r];
        const float xi = dd[ctl * 3 + 2][r];
        const float si = __builtin_amdgcn_rcpf(1.f + __expf(-xi));
        const float th = 1.f - 2.f * __builtin_amdgcn_rcpf(__expf(2.f * xg) + 1.f);
        const float so = __builtin_amdgcn_rcpf(1.f + __expf(-xo));
        const float mo = ((const float*)&mold)[r];
        const float nmv = (1.f - si) * mo + si * th;
        ((float*)&nm)[r] = nmv;
        ((float*)&nh)[r] = so * nmv;
      }
      *(float4*)(out + (b * 64 + c) * 1024 + px) = nh;
      *(float4*)(out + 1048576 + (b * 64 + c) * 1024 + px) = nm;
    }
  }
}

// ---------------------------------------------------------------------------
extern "C" void kernel_launch(void* const* d_in, const int* in_sizes, int n_in,
                              void* d_out, int out_size, void* d_ws, size_t ws_size,
                              hipStream_t stream) {
  const float* h   = (const float*)d_in[0];
  const float* m   = (const float*)d_in[1];
  const float* Wq  = (const float*)d_in[2];
  const float* bq  = (const float*)d_in[3];
  const float* Wk  = (const float*)d_in[4];
  const float* bk  = (const float*)d_in[5];
  const float* Wk2 = (const float*)d_in[6];
  const float* bk2 = (const float*)d_in[7];
  const float* Wv  = (const float*)d_in[8];
  const float* bv  = (const float*)d_in[9];
  const float* Wv2 = (const float*)d_in[10];
  const float* bv2 = (const float*)d_in[11];
  const float* Wz  = (const float*)d_in[12];
  const float* bz  = (const float*)d_in[13];
  const float* Wm  = (const float*)d_in[14];
  const float* bm  = (const float*)d_in[15];
  float* out = (float*)d_out;

  char* ws = (char*)d_ws;
  const size_t MB = 1024 * 1024;
  u16* Qb   = (u16*)(ws + 0 * MB);       // (B,N,64)
  u16* Khb  = (u16*)(ws + 2 * MB);
  u16* Kmb  = (u16*)(ws + 4 * MB);
  u16* Vhb  = (u16*)(ws + 6 * MB);       // (B,C,N)
  u16* Vmb  = (u16*)(ws + 8 * MB);
  u16* hbuf = (u16*)(ws + 10 * MB);      // (B,N,64)
  u16* Ztb  = (u16*)(ws + 12 * MB);      // (B,N,128)
  u16* W5   = (u16*)(ws + 16 * MB);               // 5x 64x64 bf16
  u16* Wzb  = (u16*)(ws + 16 * MB + 40960);       // 128x128
  u16* Wmb  = (u16*)(ws + 16 * MB + 73728);       // 192x192 permuted
  float* bmp = (float*)(ws + 16 * MB + 147456);   // 192 permuted

  prep_kernel<<<289, 256, 0, stream>>>(Wq, Wk, Wk2, Wv, Wv2, Wz, Wm, bm,
                                       W5, Wzb, Wmb, bmp);
  proj_kernel<<<dim3(16, 16, 2), 256, 0, stream>>>(h, m, bq, bk, bk2, bv, bv2, W5,
                                                   Qb, Khb, Kmb, Vhb, Vmb, hbuf);
  attn_kernel<<<512, 256, 0, stream>>>(Qb, Khb, Kmb, Vhb, Vmb, Ztb);
  tail_kernel<<<dim3(32, 16), 256, 0, stream>>>(Ztb, hbuf, m, Wzb, bz, Wmb, bmp, out);
}